// Round 9
// baseline (4135.515 us; speedup 1.0000x reference)
//
#include <hip/hip_runtime.h>

// LSTM B=64 T=512 I=512 H=1024 — round 16.
// R15 post-mortem (+47%): late publish put the publisher's x-phase INSIDE the
// inter-block recurrence chain (publish_last->detect->stage->consume->gate->
// publish). Twice-confirmed rule: publish ASAP (end of iter, right after
// gate); only CONSUMER work may be deferred. Full revert to R13 protocol.
// R16 change (consumer side only): overlap the stage-load RTT with x-compute.
//   old: x loads+MFMAs -> poll -> stage issue -> WAIT -> sync -> consume
//   new: x loads->regs (pinned, drained during publish wait) -> poll ->
//        stage issue -> x MFMAs (regs only, run under stage flight; accs are
//        "+v" operands of the stage wait so they can't sink past it) ->
//        WAIT -> ds_write -> sync -> consume -> red -> gate -> publish.
// Removes min(stageRTT, xMFMA) ~0.3-0.4us/step from the chain and detects
// ~0.2us earlier. Publish timing identical to R13 => safety induction holds
// (publish follows red-syncthreads proving all 8 waves drained h loads).

typedef short bf16x8 __attribute__((ext_vector_type(8)));
typedef float f32x4  __attribute__((ext_vector_type(4)));
typedef unsigned u32x4 __attribute__((ext_vector_type(4)));

#define BB 64
#define TT 512
#define II 512
#define HH 1024

#define NBLK 256
#define NTHR 512

// ws layout (bytes)
#define WS_CNT_OFF   0                       // 16 counters, 256B apart (memset 8K)
#define WS_HPAKH_OFF 8192                    // u16 [2][HH/8][BB][8] = 256 KB
#define WS_HPAKL_OFF (8192 + 262144)
#define WS_XPAKH_OFF (1 << 20)               // u16 [TT][II/8][BB][8] = 32 MB
#define WS_XPAKL_OFF ((1 << 20) + (32u << 20))

#define HBUF_STRIDE 65536                    // u16 per h buffer
#define XT_STRIDE   32768                    // u16 per timestep of x

__device__ __forceinline__ int atomic_add_rlx(int* p) {
    return __hip_atomic_fetch_add(p, 1, __ATOMIC_RELAXED, __HIP_MEMORY_SCOPE_AGENT);
}
__device__ __forceinline__ int load_rlx(const int* p) {
    return __hip_atomic_load(p, __ATOMIC_RELAXED, __HIP_MEMORY_SCOPE_AGENT);
}
__device__ __forceinline__ void store_wt_u16(unsigned short* p, unsigned short v) {
    __hip_atomic_store(p, v, __ATOMIC_RELAXED, __HIP_MEMORY_SCOPE_AGENT);
}

__device__ __forceinline__ float fast_sigmoid(float x) {
    return 1.0f / (1.0f + __expf(-x));
}
__device__ __forceinline__ float fast_tanh(float x) {
    x = fminf(15.0f, fmaxf(-15.0f, x));
    const float e = __expf(2.0f * x);
    return (e - 1.0f) / (e + 1.0f);
}

// fp32 -> bf16 hi + bf16 lo-of-residual (RNE both)
__device__ __forceinline__ void split_bf16(float x, unsigned& hi, unsigned& lo)
{
    unsigned b = __float_as_uint(x);
    hi = (b + 0x7fffu + ((b >> 16) & 1u)) >> 16;
    float r = x - __uint_as_float(hi << 16);
    unsigned bl = __float_as_uint(r);
    lo = (bl + 0x7fffu + ((bl >> 16) & 1u)) >> 16;
}

#define MFMA(A, B, C) __builtin_amdgcn_mfma_f32_16x16x32_bf16((A), (B), (C), 0, 0, 0)

// coherent 16B load, issued WITHOUT wait (MUST pair with WAITSTG below)
__device__ __forceinline__ void issue_coh(const unsigned short* p, u32x4& d)
{
    asm volatile("global_load_dwordx4 %0, %1, off sc0 sc1" : "=v"(d) : "v"(p));
}
// pin x fragments into registers (forces compiler to complete loads here)
#define PINX(XA)                                                              \
    asm volatile(""                                                           \
        : "+v"(XA[0][0]), "+v"(XA[0][1]), "+v"(XA[1][0]), "+v"(XA[1][1]),     \
          "+v"(XA[2][0]), "+v"(XA[2][1]), "+v"(XA[3][0]), "+v"(XA[3][1]))
// drain all VMEM; stage values AND x-accumulators flow THROUGH the wait, so
// stage uses can't hoist above it and x MFMAs can't sink below it
#define WAITSTG(FH, FL, S0, S12)                                              \
    asm volatile("s_waitcnt vmcnt(0)"                                         \
        : "+v"(FH[0]), "+v"(FH[1]), "+v"(FH[2]), "+v"(FH[3]),                 \
          "+v"(FL[0]), "+v"(FL[1]), "+v"(FL[2]), "+v"(FL[3]),                 \
          "+v"(S0[0]), "+v"(S0[1]), "+v"(S12[0]), "+v"(S12[1])                \
        :: "memory")

// x -> split planes, layout [t][k>>3][b][k&7] u16 per plane
__global__ void __launch_bounds__(256)
transpose_pack_x(const float* __restrict__ x,
                 unsigned short* __restrict__ xH, unsigned short* __restrict__ xL)
{
    __shared__ float tile[64][65];
    const int t   = (int)blockIdx.x;
    const int tid = (int)threadIdx.x;
    const int li  = tid & 63;
    const int w4  = tid >> 6;

    for (int kc = 0; kc < II; kc += 64) {
#pragma unroll
        for (int r = 0; r < 16; ++r) {
            const int b = w4 * 16 + r;
            tile[b][li] = x[((size_t)b * TT + t) * II + kc + li];
        }
        __syncthreads();
#pragma unroll
        for (int half = 0; half < 2; ++half) {
            const int u  = tid + half * 256;      // u = k8*64 + b
            const int k8 = u >> 6, b = u & 63;
            unsigned short oh[8], ol[8];
#pragma unroll
            for (int e = 0; e < 8; ++e) {
                unsigned hi, lo;
                split_bf16(tile[b][k8 * 8 + e], hi, lo);
                oh[e] = (unsigned short)hi;
                ol[e] = (unsigned short)lo;
            }
            const size_t idx = (size_t)t * XT_STRIDE + ((kc >> 3) + k8) * 512 + b * 8;
            *(uint4*)(xH + idx) = *(const uint4*)oh;
            *(uint4*)(xL + idx) = *(const uint4*)ol;
        }
        __syncthreads();
    }
}

__global__ void __launch_bounds__(NTHR, 2)   // <=256 VGPR, 1 block/CU
lstm_mfma(const unsigned short* __restrict__ xH,
          const unsigned short* __restrict__ xL,
          const int*   __restrict__ lens,
          const float* __restrict__ Wih,     // [4H][I]
          const float* __restrict__ Whh,     // [4H][H]
          const float* __restrict__ bih,
          const float* __restrict__ bhh,
          unsigned short* __restrict__ hH,   // [2][H/8][B][8]
          unsigned short* __restrict__ hL,
          int*   __restrict__ cnts,          // 16 counters, 64-int stride
          float* __restrict__ out)           // [B][H]
{
    __shared__ float red[2][2][3][2][16][17];     // [pa][mt][kh-1][u][bsub][17] ~26KB
    __shared__ unsigned short hstg[2][128][128];  // [plane][chunk][b16*8] 64KB
    __shared__ float biaslds[4][16];              // [gate][j-within-block]
    __shared__ int hflag;                         // step-ready broadcast

    const int tid  = (int)threadIdx.x;
    const int l    = tid & 63;
    const int p    = __builtin_amdgcn_readfirstlane(tid >> 6);  // wave 0..7
    const int kh   = p & 3;                  // k-split 0..3
    const int mt   = p >> 2;                 // m-pair 0..1 (tiles mt*2+u)
    const int bsub = l & 15;
    const int q    = l >> 4;                 // quad

    const int jt = (int)blockIdx.x >> 2;     // 0..63  (16 channels each)
    const int bq = (int)blockIdx.x & 3;      // 0..3   (16 batch each)
    const int j0 = jt * 16;
    const int b0 = bq * 16;

    const int bofs = (b0 + bsub) * 8;        // u16 offset of my batch lane

    int*       prodc = cnts + (bq * 4 + (jt >> 4)) * 64;  // my quarter's counter
    const int* pollc = cnts + (bq * 4 + (l & 3)) * 64;    // poller: lane l&3's quarter

    // ---- weight A-fragments -> registers (persist across all t) ----
    bf16x8 whi[2][12], wlo[2][12];
#pragma unroll
    for (int u = 0; u < 2; ++u) {
        const int row = (l & 3) * HH + j0 + (mt * 2 + u) * 4 + ((l & 15) >> 2);
#pragma unroll
        for (int kt = 0; kt < 12; ++kt) {
            const int ktg = (kt < 4) ? (4 * kh + kt) : (16 + 8 * kh + (kt - 4));
            const float* src = (ktg < 16)
                ? (Wih + (size_t)row * II + ktg * 32 + q * 8)
                : (Whh + (size_t)row * HH + (ktg - 16) * 32 + q * 8);
            const float4 w0 = *(const float4*)src;
            const float4 w1 = *(const float4*)(src + 4);
            const float wf[8] = {w0.x, w0.y, w0.z, w0.w, w1.x, w1.y, w1.z, w1.w};
#pragma unroll
            for (int e = 0; e < 8; ++e) {
                unsigned hi, lo;
                split_bf16(wf[e], hi, lo);
                whi[u][kt][e] = (short)hi;
                wlo[u][kt][e] = (short)lo;
            }
        }
    }

    // ---- per-cell state; init h_0, ack, publish (R13 protocol) ----
    float c[2] = {0.f, 0.f}, lasth[2] = {0.f, 0.f};
    int len = 0;
    const size_t hchunk = (size_t)(2 * jt + mt) * 512;  // my output chunk row

    if (kh == 0) {
        len = lens[b0 + bsub];
#pragma unroll
        for (int u = 0; u < 2; ++u) {
            store_wt_u16(hH + hchunk + bofs + 4 * u + q, 0);   // h_0 = 0, buffer 0
            store_wt_u16(hL + hchunk + bofs + 4 * u + q, 0);
        }
        asm volatile("s_waitcnt vmcnt(0)" ::: "memory");
        if (l == 0) atomic_add_rlx(prodc);               // -> 32 when all ready
    }

    // ---- bias table + flag init before any poll ----
    if (tid < 64) {
        const int gi = tid >> 4, jj = tid & 15;
        biaslds[gi][jj] = bih[gi * HH + j0 + jj] + bhh[gi * HH + j0 + jj];
    }
    if (tid == 0)
        __hip_atomic_store(&hflag, 0, __ATOMIC_RELAXED, __HIP_MEMORY_SCOPE_WORKGROUP);
    __syncthreads();

    for (int t = 0; t < TT; ++t) {
        // ---- x loads -> registers (L2-cached; drained here, during the
        //      publish wait window) ----
        bf16x8 xa[4][2];
        {
            const unsigned short* xh = xH + (size_t)t * XT_STRIDE;
            const unsigned short* xl = xL + (size_t)t * XT_STRIDE;
#pragma unroll
            for (int xi = 0; xi < 4; ++xi) {
                const int idx = ((4 * kh + xi) * 4 + q) * 512 + bofs;
                xa[xi][0] = *(const bf16x8*)(xh + idx);
                xa[xi][1] = *(const bf16x8*)(xl + idx);
            }
            PINX(xa);
        }

        // ---- step-ready: wave 7 polls 4 quarter counters, others spin LDS ----
        {
            const int need = 32 * (t + 1);
            if (p == 7) {
                while (load_rlx(pollc) < need)       // divergent: exits when all
                    __builtin_amdgcn_s_sleep(1);     // 4 quarters (l&3) pass
                if (l == 0)
                    __hip_atomic_store(&hflag, t + 1, __ATOMIC_RELAXED,
                                       __HIP_MEMORY_SCOPE_WORKGROUP);
            } else {
                while (__hip_atomic_load(&hflag, __ATOMIC_RELAXED,
                                         __HIP_MEMORY_SCOPE_WORKGROUP) < t + 1)
                    __builtin_amdgcn_s_sleep(1);
            }
            asm volatile("" ::: "memory");
        }

        // ---- issue coherent stage loads (in flight during x-MFMAs) ----
        const unsigned short* hph = hH + (t & 1) * HBUF_STRIDE;
        const unsigned short* hpl = hL + (t & 1) * HBUF_STRIDE;
        u32x4 fh[4], fl[4];
#pragma unroll
        for (int r = 0; r < 4; ++r) {
            const int chunk = kh * 32 + mt * 16 + r * 4 + q;
            const int idx = chunk * 512 + bofs;
            issue_coh(hph + idx, fh[r]);
            issue_coh(hpl + idx, fl[r]);
        }

        // ---- x-part MFMAs from registers (overlap stage-load flight) ----
        f32x4 s0[2], s12[2];
#pragma unroll
        for (int u = 0; u < 2; ++u)
            s0[u] = s12[u] = (f32x4){0.f, 0.f, 0.f, 0.f};
#pragma unroll
        for (int xi = 0; xi < 4; ++xi)
#pragma unroll
            for (int u = 0; u < 2; ++u) {
                s0[u]  = MFMA(whi[u][xi], xa[xi][0], s0[u]);
                s12[u] = MFMA(whi[u][xi], xa[xi][1], s12[u]);
                s12[u] = MFMA(wlo[u][xi], xa[xi][0], s12[u]);
            }

        // ---- wait stage loads (x-accs flow through: MFMAs can't sink) ----
        WAITSTG(fh, fl, s0, s12);
#pragma unroll
        for (int r = 0; r < 4; ++r) {
            const int chunk = kh * 32 + mt * 16 + r * 4 + q;
            *(u32x4*)&hstg[0][chunk][bsub * 8] = fh[r];
            *(u32x4*)&hstg[1][chunk][bsub * 8] = fl[r];
        }
        __syncthreads();

        // ---- h-part consume: 8 k-steps of my quarter from LDS ----
#pragma unroll
        for (int hi2 = 0; hi2 < 8; ++hi2) {
            const int chunk = kh * 32 + hi2 * 4 + q;
            const bf16x8 ahi = *(const bf16x8*)&hstg[0][chunk][bsub * 8];
            const bf16x8 alo = *(const bf16x8*)&hstg[1][chunk][bsub * 8];
#pragma unroll
            for (int u = 0; u < 2; ++u) {
                s0[u]  = MFMA(whi[u][4 + hi2], ahi, s0[u]);
                s12[u] = MFMA(whi[u][4 + hi2], alo, s12[u]);
                s12[u] = MFMA(wlo[u][4 + hi2], ahi, s12[u]);
            }
        }

        // ---- merge streams + single-phase cross-wave reduction ----
        f32x4 acc[2];
#pragma unroll
        for (int u = 0; u < 2; ++u) acc[u] = s0[u] + s12[u];
        const int pa = t & 1;

        if (kh != 0) {
#pragma unroll
            for (int u = 0; u < 2; ++u)
#pragma unroll
                for (int i = 0; i < 4; ++i)
                    red[pa][mt][kh - 1][u][bsub][4 * q + i] = acc[u][i];
        }
        __syncthreads();

        // ---- gate math (kh==0), h store, drain, publish — R13 exact ----
        if (kh == 0) {
            unsigned short* dsth = hH + ((t + 1) & 1) * HBUF_STRIDE + hchunk;
            unsigned short* dstl = hL + ((t + 1) & 1) * HBUF_STRIDE + hchunk;
#pragma unroll
            for (int u = 0; u < 2; ++u) {
                const int jj = (mt * 2 + u) * 4 + q;
                float g4[4];
#pragma unroll
                for (int i = 0; i < 4; ++i)
                    g4[i] = acc[u][i] + biaslds[i][jj]
                          + red[pa][mt][0][u][bsub][4 * q + i]
                          + red[pa][mt][1][u][bsub][4 * q + i]
                          + red[pa][mt][2][u][bsub][4 * q + i];
                const float ig = fast_sigmoid(g4[0]);
                const float fg = fast_sigmoid(g4[1]);
                const float gg = fast_tanh(g4[2]);
                const float og = fast_sigmoid(g4[3]);
                c[u] = fg * c[u] + ig * gg;
                const float h = og * fast_tanh(c[u]);
                unsigned hi, lo;
                split_bf16(h, hi, lo);
                store_wt_u16(dsth + bofs + 4 * u + q, (unsigned short)hi);
                store_wt_u16(dstl + bofs + 4 * u + q, (unsigned short)lo);
                if (t == len - 1) lasth[u] = h;
            }
            asm volatile("s_waitcnt vmcnt(0)" ::: "memory");  // h stores visible
            if (l == 0) atomic_add_rlx(prodc);                // publish h_{t+1}
        }
    }

    // ---- epilogue ----
    if (kh == 0) {
#pragma unroll
        for (int u = 0; u < 2; ++u) {
            const int jj = (mt * 2 + u) * 4 + q;
            out[(size_t)(b0 + bsub) * HH + j0 + jj] = lasth[u];
        }
    }
}

extern "C" void kernel_launch(void* const* d_in, const int* in_sizes, int n_in,
                              void* d_out, int out_size, void* d_ws, size_t ws_size,
                              hipStream_t stream)
{
    const float* seq  = (const float*)d_in[0];
    const int*   lens = (const int*)  d_in[1];
    const float* Wih  = (const float*)d_in[2];
    const float* Whh  = (const float*)d_in[3];
    const float* bih  = (const float*)d_in[4];
    const float* bhh  = (const float*)d_in[5];
    float* out = (float*)d_out;

    char* ws = (char*)d_ws;
    int*            cnts = (int*)           (ws + WS_CNT_OFF);
    unsigned short* hH   = (unsigned short*)(ws + WS_HPAKH_OFF);
    unsigned short* hL   = (unsigned short*)(ws + WS_HPAKL_OFF);
    unsigned short* xH   = (unsigned short*)(ws + WS_XPAKH_OFF);
    unsigned short* xL   = (unsigned short*)(ws + WS_XPAKL_OFF);

    hipMemsetAsync(cnts, 0, 8192, stream);   // monotonic counters start at 0
    transpose_pack_x<<<dim3(TT), dim3(256), 0, stream>>>(seq, xH, xL);
    lstm_mfma<<<dim3(NBLK), dim3(NTHR), 0, stream>>>(xH, xL, lens, Wih, Whh, bih, bhh,
                                                     hH, hL, cnts, out);
}

// Round 10
// 2326.307 us; speedup vs baseline: 1.7777x; 1.7777x over previous
//
#include <hip/hip_runtime.h>

// LSTM B=64 T=512 I=512 H=1024 — round 17.
// R14/R15/R16 all regressed: the R13 schedule (x-phase BEFORE poll as natural
// backoff; publish immediately after gate; nothing inserted post-detect) is
// the tuned ordering — locked. R17 keeps the R13 schedule byte-for-byte and
// shrinks the chain PAYLOAD instead: h is transported as SINGLE-PLANE bf16
// (x and weights keep the hi+lo split; they are off-chain).
//   - coherent stage burst 8 -> 4 b128 loads (h traffic 16 -> 8 MB/step)
//   - h-consume MFMAs 24 -> 16 per wave (total 36 -> 28, -22%)
//   - kh0 h-stores 4 -> 2 per thread; publish drain covers fewer stores
//   - stage LDS 64 -> 32 KB (total ~60 KB; may allow 2 blocks/CU)
// Accuracy: dropping h-lo adds bf16 noise eps<=2^-10/elem; per-gate dot error
// ~2.3e-4/step; worst-case integrator cells random-walk to ~4.5e-3 on c over
// 512 steps -> ~2e-3 on h. Predicted absmax 3-6e-3 vs 9.06e-3 threshold.
// If FAIL: revert to R13 (2460us) and declare roofline.

typedef short bf16x8 __attribute__((ext_vector_type(8)));
typedef float f32x4  __attribute__((ext_vector_type(4)));
typedef unsigned u32x4 __attribute__((ext_vector_type(4)));

#define BB 64
#define TT 512
#define II 512
#define HH 1024

#define NBLK 256
#define NTHR 512

// ws layout (bytes)
#define WS_CNT_OFF   0                       // 16 counters, 256B apart (memset 8K)
#define WS_HPAKH_OFF 8192                    // u16 [2][HH/8][BB][8] = 256 KB
#define WS_XPAKH_OFF (1 << 20)               // u16 [TT][II/8][BB][8] = 32 MB
#define WS_XPAKL_OFF ((1 << 20) + (32u << 20))

#define HBUF_STRIDE 65536                    // u16 per h buffer
#define XT_STRIDE   32768                    // u16 per timestep of x

__device__ __forceinline__ int atomic_add_rlx(int* p) {
    return __hip_atomic_fetch_add(p, 1, __ATOMIC_RELAXED, __HIP_MEMORY_SCOPE_AGENT);
}
__device__ __forceinline__ int load_rlx(const int* p) {
    return __hip_atomic_load(p, __ATOMIC_RELAXED, __HIP_MEMORY_SCOPE_AGENT);
}
__device__ __forceinline__ void store_wt_u16(unsigned short* p, unsigned short v) {
    __hip_atomic_store(p, v, __ATOMIC_RELAXED, __HIP_MEMORY_SCOPE_AGENT);
}

__device__ __forceinline__ float fast_sigmoid(float x) {
    return 1.0f / (1.0f + __expf(-x));
}
__device__ __forceinline__ float fast_tanh(float x) {
    x = fminf(15.0f, fmaxf(-15.0f, x));
    const float e = __expf(2.0f * x);
    return (e - 1.0f) / (e + 1.0f);
}

// fp32 -> bf16 hi + bf16 lo-of-residual (RNE both)
__device__ __forceinline__ void split_bf16(float x, unsigned& hi, unsigned& lo)
{
    unsigned b = __float_as_uint(x);
    hi = (b + 0x7fffu + ((b >> 16) & 1u)) >> 16;
    float r = x - __uint_as_float(hi << 16);
    unsigned bl = __float_as_uint(r);
    lo = (bl + 0x7fffu + ((bl >> 16) & 1u)) >> 16;
}
// fp32 -> bf16 (RNE), hi only
__device__ __forceinline__ unsigned short bf16_rne(float x)
{
    unsigned b = __float_as_uint(x);
    return (unsigned short)((b + 0x7fffu + ((b >> 16) & 1u)) >> 16);
}

#define MFMA(A, B, C) __builtin_amdgcn_mfma_f32_16x16x32_bf16((A), (B), (C), 0, 0, 0)

// coherent 16B load, issued WITHOUT wait (MUST pair with WAITSTG4 below)
__device__ __forceinline__ void issue_coh(const unsigned short* p, u32x4& d)
{
    asm volatile("global_load_dwordx4 %0, %1, off sc0 sc1" : "=v"(d) : "v"(p));
}
// drain all VMEM; loaded values flow THROUGH the wait so uses can't be hoisted
#define WAITSTG4(FH)                                                          \
    asm volatile("s_waitcnt vmcnt(0)"                                         \
        : "+v"(FH[0]), "+v"(FH[1]), "+v"(FH[2]), "+v"(FH[3])                  \
        :: "memory")

// x -> split planes, layout [t][k>>3][b][k&7] u16 per plane
__global__ void __launch_bounds__(256)
transpose_pack_x(const float* __restrict__ x,
                 unsigned short* __restrict__ xH, unsigned short* __restrict__ xL)
{
    __shared__ float tile[64][65];
    const int t   = (int)blockIdx.x;
    const int tid = (int)threadIdx.x;
    const int li  = tid & 63;
    const int w4  = tid >> 6;

    for (int kc = 0; kc < II; kc += 64) {
#pragma unroll
        for (int r = 0; r < 16; ++r) {
            const int b = w4 * 16 + r;
            tile[b][li] = x[((size_t)b * TT + t) * II + kc + li];
        }
        __syncthreads();
#pragma unroll
        for (int half = 0; half < 2; ++half) {
            const int u  = tid + half * 256;      // u = k8*64 + b
            const int k8 = u >> 6, b = u & 63;
            unsigned short oh[8], ol[8];
#pragma unroll
            for (int e = 0; e < 8; ++e) {
                unsigned hi, lo;
                split_bf16(tile[b][k8 * 8 + e], hi, lo);
                oh[e] = (unsigned short)hi;
                ol[e] = (unsigned short)lo;
            }
            const size_t idx = (size_t)t * XT_STRIDE + ((kc >> 3) + k8) * 512 + b * 8;
            *(uint4*)(xH + idx) = *(const uint4*)oh;
            *(uint4*)(xL + idx) = *(const uint4*)ol;
        }
        __syncthreads();
    }
}

__global__ void __launch_bounds__(NTHR, 2)
lstm_mfma(const unsigned short* __restrict__ xH,
          const unsigned short* __restrict__ xL,
          const int*   __restrict__ lens,
          const float* __restrict__ Wih,     // [4H][I]
          const float* __restrict__ Whh,     // [4H][H]
          const float* __restrict__ bih,
          const float* __restrict__ bhh,
          unsigned short* __restrict__ hH,   // [2][H/8][B][8] bf16 only
          int*   __restrict__ cnts,          // 16 counters, 64-int stride
          float* __restrict__ out)           // [B][H]
{
    __shared__ float red[2][2][3][2][16][17];     // [pa][mt][kh-1][u][bsub][17] ~26KB
    __shared__ unsigned short hstg[128][128];     // [chunk][b16*8] 32KB
    __shared__ float biaslds[4][16];              // [gate][j-within-block]
    __shared__ int hflag;                         // step-ready broadcast

    const int tid  = (int)threadIdx.x;
    const int l    = tid & 63;
    const int p    = __builtin_amdgcn_readfirstlane(tid >> 6);  // wave 0..7
    const int kh   = p & 3;                  // k-split 0..3
    const int mt   = p >> 2;                 // m-pair 0..1 (tiles mt*2+u)
    const int bsub = l & 15;
    const int q    = l >> 4;                 // quad

    const int jt = (int)blockIdx.x >> 2;     // 0..63  (16 channels each)
    const int bq = (int)blockIdx.x & 3;      // 0..3   (16 batch each)
    const int j0 = jt * 16;
    const int b0 = bq * 16;

    const int bofs = (b0 + bsub) * 8;        // u16 offset of my batch lane

    int*       prodc = cnts + (bq * 4 + (jt >> 4)) * 64;  // my quarter's counter
    const int* pollc = cnts + (bq * 4 + (l & 3)) * 64;    // poller: lane l&3's quarter

    // ---- weight A-fragments -> registers (persist across all t) ----
    bf16x8 whi[2][12], wlo[2][12];
#pragma unroll
    for (int u = 0; u < 2; ++u) {
        const int row = (l & 3) * HH + j0 + (mt * 2 + u) * 4 + ((l & 15) >> 2);
#pragma unroll
        for (int kt = 0; kt < 12; ++kt) {
            const int ktg = (kt < 4) ? (4 * kh + kt) : (16 + 8 * kh + (kt - 4));
            const float* src = (ktg < 16)
                ? (Wih + (size_t)row * II + ktg * 32 + q * 8)
                : (Whh + (size_t)row * HH + (ktg - 16) * 32 + q * 8);
            const float4 w0 = *(const float4*)src;
            const float4 w1 = *(const float4*)(src + 4);
            const float wf[8] = {w0.x, w0.y, w0.z, w0.w, w1.x, w1.y, w1.z, w1.w};
#pragma unroll
            for (int e = 0; e < 8; ++e) {
                unsigned hi, lo;
                split_bf16(wf[e], hi, lo);
                whi[u][kt][e] = (short)hi;
                wlo[u][kt][e] = (short)lo;
            }
        }
    }

    // ---- per-cell state; init h_0, ack, publish (R13 protocol) ----
    float c[2] = {0.f, 0.f}, lasth[2] = {0.f, 0.f};
    int len = 0;
    const size_t hchunk = (size_t)(2 * jt + mt) * 512;  // my output chunk row

    if (kh == 0) {
        len = lens[b0 + bsub];
#pragma unroll
        for (int u = 0; u < 2; ++u)
            store_wt_u16(hH + hchunk + bofs + 4 * u + q, 0);   // h_0 = 0, buffer 0
        asm volatile("s_waitcnt vmcnt(0)" ::: "memory");
        if (l == 0) atomic_add_rlx(prodc);               // -> 32 when all ready
    }

    // ---- bias table + flag init before any poll ----
    if (tid < 64) {
        const int gi = tid >> 4, jj = tid & 15;
        biaslds[gi][jj] = bih[gi * HH + j0 + jj] + bhh[gi * HH + j0 + jj];
    }
    if (tid == 0)
        __hip_atomic_store(&hflag, 0, __ATOMIC_RELAXED, __HIP_MEMORY_SCOPE_WORKGROUP);
    __syncthreads();

    for (int t = 0; t < TT; ++t) {
        // ---- x-part (plain cached b128 loads; independent of h_t) ----
        f32x4 s0[2], s12[2];
#pragma unroll
        for (int u = 0; u < 2; ++u)
            s0[u] = s12[u] = (f32x4){0.f, 0.f, 0.f, 0.f};
        {
            const unsigned short* xh = xH + (size_t)t * XT_STRIDE;
            const unsigned short* xl = xL + (size_t)t * XT_STRIDE;
#pragma unroll
            for (int xi = 0; xi < 4; ++xi) {
                const int idx = ((4 * kh + xi) * 4 + q) * 512 + bofs;
                const bf16x8 ahi = *(const bf16x8*)(xh + idx);
                const bf16x8 alo = *(const bf16x8*)(xl + idx);
#pragma unroll
                for (int u = 0; u < 2; ++u) {
                    s0[u]  = MFMA(whi[u][xi], ahi, s0[u]);
                    s12[u] = MFMA(whi[u][xi], alo, s12[u]);
                    s12[u] = MFMA(wlo[u][xi], ahi, s12[u]);
                }
            }
        }

        // ---- step-ready: wave 7 polls 4 quarter counters, others spin LDS ----
        {
            const int need = 32 * (t + 1);
            if (p == 7) {
                while (load_rlx(pollc) < need)       // divergent: exits when all
                    __builtin_amdgcn_s_sleep(1);     // 4 quarters (l&3) pass
                if (l == 0)
                    __hip_atomic_store(&hflag, t + 1, __ATOMIC_RELAXED,
                                       __HIP_MEMORY_SCOPE_WORKGROUP);
            } else {
                while (__hip_atomic_load(&hflag, __ATOMIC_RELAXED,
                                         __HIP_MEMORY_SCOPE_WORKGROUP) < t + 1)
                    __builtin_amdgcn_s_sleep(1);
            }
            asm volatile("" ::: "memory");
        }

        // ---- h-part stage: each wave coherently loads its 16 chunks ----
        const unsigned short* hph = hH + (t & 1) * HBUF_STRIDE;
        {
            u32x4 fh[4];
#pragma unroll
            for (int r = 0; r < 4; ++r) {
                const int chunk = kh * 32 + mt * 16 + r * 4 + q;
                issue_coh(hph + chunk * 512 + bofs, fh[r]);
            }
            WAITSTG4(fh);
#pragma unroll
            for (int r = 0; r < 4; ++r) {
                const int chunk = kh * 32 + mt * 16 + r * 4 + q;
                *(u32x4*)&hstg[chunk][bsub * 8] = fh[r];
            }
        }
        __syncthreads();

        // ---- h-part consume: 8 k-steps of my quarter from LDS (2 streams) ----
#pragma unroll
        for (int hi2 = 0; hi2 < 8; ++hi2) {
            const int chunk = kh * 32 + hi2 * 4 + q;
            const bf16x8 ahi = *(const bf16x8*)&hstg[chunk][bsub * 8];
#pragma unroll
            for (int u = 0; u < 2; ++u) {
                s0[u]  = MFMA(whi[u][4 + hi2], ahi, s0[u]);
                s12[u] = MFMA(wlo[u][4 + hi2], ahi, s12[u]);
            }
        }

        // ---- merge streams + single-phase cross-wave reduction ----
        f32x4 acc[2];
#pragma unroll
        for (int u = 0; u < 2; ++u) acc[u] = s0[u] + s12[u];
        const int pa = t & 1;

        if (kh != 0) {
#pragma unroll
            for (int u = 0; u < 2; ++u)
#pragma unroll
                for (int i = 0; i < 4; ++i)
                    red[pa][mt][kh - 1][u][bsub][4 * q + i] = acc[u][i];
        }
        __syncthreads();

        // ---- gate math (kh==0), h store, drain, publish — R13 exact ----
        if (kh == 0) {
            unsigned short* dsth = hH + ((t + 1) & 1) * HBUF_STRIDE + hchunk;
#pragma unroll
            for (int u = 0; u < 2; ++u) {
                const int jj = (mt * 2 + u) * 4 + q;
                float g4[4];
#pragma unroll
                for (int i = 0; i < 4; ++i)
                    g4[i] = acc[u][i] + biaslds[i][jj]
                          + red[pa][mt][0][u][bsub][4 * q + i]
                          + red[pa][mt][1][u][bsub][4 * q + i]
                          + red[pa][mt][2][u][bsub][4 * q + i];
                const float ig = fast_sigmoid(g4[0]);
                const float fg = fast_sigmoid(g4[1]);
                const float gg = fast_tanh(g4[2]);
                const float og = fast_sigmoid(g4[3]);
                c[u] = fg * c[u] + ig * gg;
                const float h = og * fast_tanh(c[u]);
                store_wt_u16(dsth + bofs + 4 * u + q, bf16_rne(h));
                if (t == len - 1) lasth[u] = h;
            }
            asm volatile("s_waitcnt vmcnt(0)" ::: "memory");  // h stores visible
            if (l == 0) atomic_add_rlx(prodc);                // publish h_{t+1}
        }
    }

    // ---- epilogue ----
    if (kh == 0) {
#pragma unroll
        for (int u = 0; u < 2; ++u) {
            const int jj = (mt * 2 + u) * 4 + q;
            out[(size_t)(b0 + bsub) * HH + j0 + jj] = lasth[u];
        }
    }
}

extern "C" void kernel_launch(void* const* d_in, const int* in_sizes, int n_in,
                              void* d_out, int out_size, void* d_ws, size_t ws_size,
                              hipStream_t stream)
{
    const float* seq  = (const float*)d_in[0];
    const int*   lens = (const int*)  d_in[1];
    const float* Wih  = (const float*)d_in[2];
    const float* Whh  = (const float*)d_in[3];
    const float* bih  = (const float*)d_in[4];
    const float* bhh  = (const float*)d_in[5];
    float* out = (float*)d_out;

    char* ws = (char*)d_ws;
    int*            cnts = (int*)           (ws + WS_CNT_OFF);
    unsigned short* hH   = (unsigned short*)(ws + WS_HPAKH_OFF);
    unsigned short* xH   = (unsigned short*)(ws + WS_XPAKH_OFF);
    unsigned short* xL   = (unsigned short*)(ws + WS_XPAKL_OFF);

    hipMemsetAsync(cnts, 0, 8192, stream);   // monotonic counters start at 0
    transpose_pack_x<<<dim3(TT), dim3(256), 0, stream>>>(seq, xH, xL);
    lstm_mfma<<<dim3(NBLK), dim3(NTHR), 0, stream>>>(xH, xL, lens, Wih, Whh, bih, bhh,
                                                     hH, cnts, out);
}